// Round 1
// baseline (2798.675 us; speedup 1.0000x reference)
//
#include <hip/hip_runtime.h>
#include <hip/hip_bf16.h>
#include <math.h>

constexpr int N = 65536;
constexpr int C = 192;
constexpr int O = 192;
constexpr int H = 384;
constexpr int E = 8;
constexpr int B = 4;
constexpr int R = 8;
constexpr int F = 64;
constexpr int GIN = C + F + 2;   // 258
constexpr int K = 10240;
constexpr int TM = 16;           // tokens per expert-tile

// ---------- helpers ----------
__device__ inline unsigned long long dkey(double d) {
  unsigned long long u = (unsigned long long)__double_as_longlong(d);
  return (u & 0x8000000000000000ULL) ? ~u : (u | 0x8000000000000000ULL);
}

__device__ inline double wave_reduce_sum(double v) {
  #pragma unroll
  for (int off = 32; off; off >>= 1) v += __shfl_down(v, off);
  return v;  // valid on lane 0
}

// ---------- gate: Z = x@Wz (f64), residual stats, LN, logits ----------
__global__ __launch_bounds__(512) void gate_kernel(
    const float* __restrict__ x, const float* __restrict__ xp,
    const float* __restrict__ Wz, const float* __restrict__ ln_g,
    const float* __restrict__ ln_b, const float* __restrict__ Wg,
    const float* __restrict__ bg, double* __restrict__ logitsD,
    double* __restrict__ logitsT) {
  __shared__ float Wzs[C * F];      // 48 KiB
  __shared__ float Wgs[GIN * E];    // ~8 KiB
  __shared__ float gs[GIN];
  __shared__ float bs[GIN];
  __shared__ float bgs[E];
  __shared__ float xsh[8][C];

  int tid = threadIdx.x;
  for (int i = tid; i < C * F; i += 512) Wzs[i] = Wz[i];
  for (int i = tid; i < GIN * E; i += 512) Wgs[i] = Wg[i];
  for (int i = tid; i < GIN; i += 512) { gs[i] = ln_g[i]; bs[i] = ln_b[i]; }
  if (tid < E) bgs[tid] = bg[tid];

  int wv = tid >> 6, lane = tid & 63;
  int n = blockIdx.x * 8 + wv;
  for (int i = lane; i < C; i += 64) xsh[wv][i] = x[(size_t)n * C + i];
  __syncthreads();

  // Z[lane] in f64
  double z = 0.0;
  for (int c = 0; c < C; ++c)
    z += (double)xsh[wv][c] * (double)Wzs[c * F + lane];

  // residual-hint stats: a = |x - x_prev|, mean + unbiased std over C
  double sa = 0.0, sa2 = 0.0;
  for (int i = lane; i < C; i += 64) {
    float d = xsh[wv][i] - xp[(size_t)n * C + i];
    float a = fabsf(d);
    sa += (double)a; sa2 += (double)a * (double)a;
  }
  #pragma unroll
  for (int off = 32; off; off >>= 1) {
    sa += __shfl_down(sa, off);
    sa2 += __shfl_down(sa2, off);
  }
  sa = __shfl(sa, 0); sa2 = __shfl(sa2, 0);
  double mean_a = sa * (1.0 / 192.0);
  double var_a = (sa2 - sa * sa * (1.0 / 192.0)) * (1.0 / 191.0);
  var_a = var_a > 0.0 ? var_a : 0.0;
  double mu = log1p(mean_a);
  double sdl = log1p(sqrt(var_a));

  // LayerNorm stats over et = [x(192), Z(64), mu, sd]
  double s = z, s2 = z * z;
  for (int i = lane; i < C; i += 64) {
    double v = (double)xsh[wv][i];
    s += v; s2 += v * v;
  }
  if (lane == 0) { s += mu; s2 += mu * mu; }
  if (lane == 1) { s += sdl; s2 += sdl * sdl; }
  #pragma unroll
  for (int off = 32; off; off >>= 1) {
    s += __shfl_down(s, off);
    s2 += __shfl_down(s2, off);
  }
  s = __shfl(s, 0); s2 = __shfl(s2, 0);
  double m_ = s * (1.0 / 258.0);
  double v_ = s2 * (1.0 / 258.0) - m_ * m_;
  v_ = v_ > 0.0 ? v_ : 0.0;
  double rstd = 1.0 / sqrt(v_ + 1e-5);

  // logits = LN(et) @ Wg + bg  (f64 accumulate)
  double acc[E] = {0, 0, 0, 0, 0, 0, 0, 0};
  for (int i = lane; i < C; i += 64) {
    double nv = ((double)xsh[wv][i] - m_) * rstd * (double)gs[i] + (double)bs[i];
    #pragma unroll
    for (int e = 0; e < E; ++e) acc[e] += nv * (double)Wgs[i * E + e];
  }
  {
    int i = 192 + lane;
    double nv = (z - m_) * rstd * (double)gs[i] + (double)bs[i];
    #pragma unroll
    for (int e = 0; e < E; ++e) acc[e] += nv * (double)Wgs[i * E + e];
  }
  if (lane == 0) {
    double nv = (mu - m_) * rstd * (double)gs[256] + (double)bs[256];
    #pragma unroll
    for (int e = 0; e < E; ++e) acc[e] += nv * (double)Wgs[256 * E + e];
  }
  if (lane == 1) {
    double nv = (sdl - m_) * rstd * (double)gs[257] + (double)bs[257];
    #pragma unroll
    for (int e = 0; e < E; ++e) acc[e] += nv * (double)Wgs[257 * E + e];
  }
  #pragma unroll
  for (int e = 0; e < E; ++e) {
    double v = acc[e];
    #pragma unroll
    for (int off = 32; off; off >>= 1) v += __shfl_down(v, off);
    if (lane == 0) {
      double lg = v + (double)bgs[e];
      logitsD[(size_t)n * E + e] = lg;
      logitsT[(size_t)e * N + n] = lg;
    }
  }
}

// ---------- per-expert exact top-K threshold via radix select ----------
__global__ __launch_bounds__(256) void select_kernel(
    const double* __restrict__ logitsT, unsigned long long* __restrict__ Tkey,
    int* __restrict__ tieCut) {
  int e = blockIdx.x;
  const double* L = logitsT + (size_t)e * N;
  __shared__ unsigned int hist[256];
  __shared__ unsigned long long spref;
  __shared__ int srem;
  __shared__ int sscan[256];
  int tid = threadIdx.x;
  if (tid == 0) { spref = 0ULL; srem = K; }
  __syncthreads();

  for (int pass = 7; pass >= 0; --pass) {
    hist[tid] = 0;
    __syncthreads();
    unsigned long long pref = spref;
    unsigned long long mhi = (pass == 7) ? 0ULL : (~0ULL << ((pass + 1) * 8));
    for (int i = tid; i < N; i += 256) {
      unsigned long long k = dkey(L[i]);
      if ((k & mhi) == pref)
        atomicAdd(&hist[(unsigned)((k >> (pass * 8)) & 0xFF)], 1u);
    }
    __syncthreads();
    if (tid == 0) {
      int rem = srem;
      int b = 255;
      for (; b > 0; --b) {
        int c = (int)hist[b];
        if (c >= rem) break;
        rem -= c;
      }
      srem = rem;
      spref = pref | ((unsigned long long)(unsigned)b << (pass * 8));
    }
    __syncthreads();
  }
  unsigned long long T = spref;
  int need = srem;  // number of ==T tokens to take (lowest indices), >= 1

  // count ==T matches per contiguous 256-token chunk, scan, find cut index
  int base = tid * (N / 256);
  int c = 0;
  for (int i = 0; i < N / 256; ++i) c += (dkey(L[base + i]) == T) ? 1 : 0;
  sscan[tid] = c;
  __syncthreads();
  for (int off = 1; off < 256; off <<= 1) {
    int v = sscan[tid];
    int add = (tid >= off) ? sscan[tid - off] : 0;
    __syncthreads();
    sscan[tid] = v + add;
    __syncthreads();
  }
  int incl = sscan[tid];
  int excl = incl - c;
  if (excl < need && need <= incl) {
    int target = need - 1 - excl;
    int seen = 0;
    for (int i = 0; i < N / 256; ++i) {
      if (dkey(L[base + i]) == T) {
        if (seen == target) { tieCut[e] = base + i; break; }
        ++seen;
      }
    }
  }
  if (tid == 0) Tkey[e] = T;
}

// ---------- routing: mask, uncovered fallback, top-2 softmax, dispatch ----------
__global__ __launch_bounds__(256) void route_kernel(
    const double* __restrict__ logitsD, const unsigned long long* __restrict__ Tkey,
    const int* __restrict__ tieCut, int* __restrict__ cnt,
    int* __restrict__ list_tok, float* __restrict__ list_w,
    double* __restrict__ importance) {
  int n = blockIdx.x * 256 + threadIdx.x;
  double l[E];
  unsigned selbits = 0;
  #pragma unroll
  for (int e = 0; e < E; ++e) {
    l[e] = logitsD[(size_t)n * E + e];
    unsigned long long k = dkey(l[e]);
    unsigned long long T = Tkey[e];
    bool sel = (k > T) || (k == T && n <= tieCut[e]);
    if (sel) selbits |= (1u << e);
  }
  if (selbits == 0) {
    int best = 0; double bv = l[0];
    #pragma unroll
    for (int e = 1; e < E; ++e) if (l[e] > bv) { bv = l[e]; best = e; }
    selbits = (1u << best);
  }
  // stable top-2 among selected
  int i0 = -1, i1 = -1;
  double v0 = -1e300, v1 = -1e300;
  #pragma unroll
  for (int e = 0; e < E; ++e) {
    if (selbits & (1u << e)) {
      double v = l[e];
      if (v > v0) { v1 = v0; i1 = i0; v0 = v; i0 = e; }
      else if (v > v1) { v1 = v; i1 = e; }
    }
  }
  double w0 = 1.0, w1 = 0.0;
  if (i1 >= 0) {
    double e1 = exp(v1 - v0);
    w0 = 1.0 / (1.0 + e1);
    w1 = e1 / (1.0 + e1);
  }
  float w0f = (float)w0;
  float w1f = (float)w1;
  bool app1 = (i1 >= 0) && (w1f > 0.0f);

  int p0 = atomicAdd(&cnt[i0], 1);
  list_tok[i0 * N + p0] = n;
  list_w[i0 * N + p0] = w0f;
  if (app1) {
    int p1 = atomicAdd(&cnt[i1], 1);
    list_tok[i1 * N + p1] = n;
    list_w[i1 * N + p1] = w1f;
  }
  // importance: per-wave reduce then one f64 atomic per expert per wave
  #pragma unroll
  for (int e = 0; e < E; ++e) {
    double v = 0.0;
    if (i0 == e) v += (double)w0f;
    if (app1 && i1 == e) v += (double)w1f;
    v = wave_reduce_sum(v);
    if ((threadIdx.x & 63) == 0 && v != 0.0)
      unsafeAtomicAdd(&importance[e], v);
  }
}

// ---------- fused expert MLP (f32) over dispatched token tiles ----------
__global__ __launch_bounds__(256) void expert_kernel(
    const float* __restrict__ x, const float* __restrict__ bw,
    const float* __restrict__ W1, const float* __restrict__ b1,
    const float* __restrict__ W2, const float* __restrict__ b2,
    const float* __restrict__ A1, const float* __restrict__ B1,
    const float* __restrict__ A2, const float* __restrict__ B2,
    const int* __restrict__ cnt, const int* __restrict__ list_tok,
    const float* __restrict__ list_w, float* __restrict__ out) {
  int e = blockIdx.y;
  int ce = cnt[e];
  int start = blockIdx.x * TM;
  if (start >= ce) return;
  int m = ce - start; if (m > TM) m = TM;

  __shared__ float xs[TM][C];    // 12 KiB
  __shared__ float hs[TM][H];    // 24 KiB
  __shared__ float t1w[TM][32];
  __shared__ float t2w[TM][32];
  __shared__ float bws[TM][B];
  __shared__ int stok[TM];
  __shared__ float swt[TM];

  int tid = threadIdx.x;
  if (tid < TM) {
    int idx = (tid < m) ? (start + tid) : start;
    stok[tid] = list_tok[e * N + idx];
    swt[tid] = (tid < m) ? list_w[e * N + idx] : 0.0f;
  }
  __syncthreads();
  for (int i = tid; i < TM * C; i += 256) {
    int t = i / C, c = i % C;
    xs[t][c] = x[(size_t)stok[t] * C + c];
  }
  if (tid < TM * B) {
    int t = tid >> 2, b = tid & 3;
    bws[t][b] = bw[(size_t)stok[t] * B + b];
  }
  __syncthreads();

  // t1w[t][b*8+r] = (sum_c x[t][c] * A1[e,b,c,r]) * bw[t][b]
  for (int id = tid; id < TM * 32; id += 256) {
    int t = id >> 5, br = id & 31, b = br >> 3, r = br & 7;
    const float* Ap = A1 + (((size_t)e * B + b) * C) * R + r;
    float acc = 0.0f;
    #pragma unroll 4
    for (int c = 0; c < C; ++c) acc += xs[t][c] * Ap[c * R];
    t1w[t][br] = acc * bws[t][b];
  }
  __syncthreads();

  // hs init = b1 + 2 * u1   (u1 = t1w @ B1f[32,H])
  for (int i = tid; i < TM * H; i += 256) {
    int t = i / H, h = i % H;
    const float* Bp = B1 + ((size_t)e * 32) * H + h;
    float acc = 0.0f;
    #pragma unroll
    for (int br = 0; br < 32; ++br) acc += t1w[t][br] * Bp[br * H];
    hs[t][h] = b1[e * H + h] + 2.0f * acc;
  }
  __syncthreads();

  // mm1: x @ W1 -> add init -> gelu(exact) -> hs
  int tx = tid & 31, ty = tid >> 5;
  int t0 = ty * 2, t1i = ty * 2 + 1;
  float acc1[2][12];
  #pragma unroll
  for (int j = 0; j < 12; ++j) { acc1[0][j] = 0.0f; acc1[1][j] = 0.0f; }
  const float* W1e = W1 + (size_t)e * C * H;
  for (int k = 0; k < C; ++k) {
    float x0 = xs[t0][k], x1 = xs[t1i][k];
    const float* Wr = W1e + (size_t)k * H + tx;
    #pragma unroll
    for (int j = 0; j < 12; ++j) {
      float w = Wr[32 * j];
      acc1[0][j] += x0 * w;
      acc1[1][j] += x1 * w;
    }
  }
  float init0[12], init1[12];
  #pragma unroll
  for (int j = 0; j < 12; ++j) {
    init0[j] = hs[t0][tx + 32 * j];
    init1[j] = hs[t1i][tx + 32 * j];
  }
  __syncthreads();
  #pragma unroll
  for (int j = 0; j < 12; ++j) {
    float v0 = acc1[0][j] + init0[j];
    float v1 = acc1[1][j] + init1[j];
    hs[t0][tx + 32 * j] = 0.5f * v0 * (1.0f + erff(v0 * 0.70710678118654752f));
    hs[t1i][tx + 32 * j] = 0.5f * v1 * (1.0f + erff(v1 * 0.70710678118654752f));
  }
  __syncthreads();

  // t2w[t][b*8+r] = (sum_h h[t][h] * A2[e,b,h,r]) * bw[t][b]
  for (int id = tid; id < TM * 32; id += 256) {
    int t = id >> 5, br = id & 31, b = br >> 3, r = br & 7;
    const float* Ap = A2 + (((size_t)e * B + b) * H) * R + r;
    float acc = 0.0f;
    #pragma unroll 4
    for (int h = 0; h < H; ++h) acc += hs[t][h] * Ap[h * R];
    t2w[t][br] = acc * bws[t][b];
  }
  __syncthreads();

  // mm2: h @ W2 + b2 + 2*u2, scaled by gate weight, atomic into out
  float acc2[2][6];
  #pragma unroll
  for (int j = 0; j < 6; ++j) { acc2[0][j] = 0.0f; acc2[1][j] = 0.0f; }
  const float* W2e = W2 + (size_t)e * H * O;
  for (int k = 0; k < H; ++k) {
    float h0 = hs[t0][k], h1 = hs[t1i][k];
    const float* Wr = W2e + (size_t)k * O + tx;
    #pragma unroll
    for (int j = 0; j < 6; ++j) {
      float w = Wr[32 * j];
      acc2[0][j] += h0 * w;
      acc2[1][j] += h1 * w;
    }
  }
  const float* B2e = B2 + (size_t)e * 32 * O;
  #pragma unroll
  for (int j = 0; j < 6; ++j) {
    int o = tx + 32 * j;
    const float* Bp = B2e + o;
    float u2a = 0.0f, u2b = 0.0f;
    #pragma unroll
    for (int br = 0; br < 32; ++br) {
      float w = Bp[br * O];
      u2a += t2w[t0][br] * w;
      u2b += t2w[t1i][br] * w;
    }
    float bb = b2[e * O + o];
    float y0 = acc2[0][j] + bb + 2.0f * u2a;
    float y1 = acc2[1][j] + bb + 2.0f * u2b;
    if (t0 < m) unsafeAtomicAdd(&out[(size_t)stok[t0] * O + o], swt[t0] * y0);
    if (t1i < m) unsafeAtomicAdd(&out[(size_t)stok[t1i] * O + o], swt[t1i] * y1);
  }
}

// ---------- load-balance aux loss ----------
__global__ void loss_kernel(const double* __restrict__ importance,
                            const int* __restrict__ cnt,
                            float* __restrict__ loss_out) {
  if (threadIdx.x == 0 && blockIdx.x == 0) {
    double im = 0.0, lm = 0.0;
    for (int e = 0; e < E; ++e) { im += importance[e]; lm += (double)cnt[e]; }
    im *= (1.0 / E); lm *= (1.0 / E);
    double iv = 0.0, lv = 0.0;
    for (int e = 0; e < E; ++e) {
      double di = importance[e] - im; iv += di * di;
      double dl = (double)cnt[e] - lm; lv += dl * dl;
    }
    iv *= (1.0 / E); lv *= (1.0 / E);
    double loss = (iv / (im * im + 1e-10) + lv / (lm * lm + 1e-10)) * 0.01;
    loss_out[0] = (float)loss;
  }
}

extern "C" void kernel_launch(void* const* d_in, const int* in_sizes, int n_in,
                              void* d_out, int out_size, void* d_ws, size_t ws_size,
                              hipStream_t stream) {
  const float* x    = (const float*)d_in[0];
  const float* bw   = (const float*)d_in[1];
  const float* xp   = (const float*)d_in[2];
  const float* Wz   = (const float*)d_in[3];
  const float* ln_g = (const float*)d_in[4];
  const float* ln_b = (const float*)d_in[5];
  const float* Wg   = (const float*)d_in[6];
  const float* bg   = (const float*)d_in[7];
  const float* W1   = (const float*)d_in[8];
  const float* b1   = (const float*)d_in[9];
  const float* W2   = (const float*)d_in[10];
  const float* b2   = (const float*)d_in[11];
  const float* A1   = (const float*)d_in[12];
  const float* B1   = (const float*)d_in[13];
  const float* A2   = (const float*)d_in[14];
  const float* B2   = (const float*)d_in[15];
  float* out = (float*)d_out;

  char* ws = (char*)d_ws;
  double* logitsD = (double*)(ws);                                 // 4 MiB
  double* logitsT = (double*)(ws + (size_t)4 * 1024 * 1024);       // 4 MiB
  int*    list_tok = (int*)(ws + (size_t)8 * 1024 * 1024);         // 2 MiB
  float*  list_w   = (float*)(ws + (size_t)10 * 1024 * 1024);      // 2 MiB
  char*   hdr      = ws + (size_t)12 * 1024 * 1024;
  unsigned long long* Tkey = (unsigned long long*)hdr;             // 64 B
  int*    tieCut = (int*)(hdr + 64);                               // 32 B
  int*    cnt    = (int*)(hdr + 96);                               // 32 B
  double* importance = (double*)(hdr + 128);                       // 64 B

  hipMemsetAsync(d_out, 0, (size_t)(N * O + 1) * sizeof(float), stream);
  hipMemsetAsync(hdr + 96, 0, 96, stream);  // cnt + importance

  gate_kernel<<<N / 8, 512, 0, stream>>>(x, xp, Wz, ln_g, ln_b, Wg, bg,
                                         logitsD, logitsT);
  select_kernel<<<E, 256, 0, stream>>>(logitsT, Tkey, tieCut);
  route_kernel<<<N / 256, 256, 0, stream>>>(logitsD, Tkey, tieCut, cnt,
                                            list_tok, list_w, importance);
  expert_kernel<<<dim3(N / TM, E), 256, 0, stream>>>(
      x, bw, W1, b1, W2, b2, A1, B1, A2, B2, cnt, list_tok, list_w, out);
  loss_kernel<<<1, 64, 0, stream>>>(importance, cnt, out + (size_t)N * O);
}

// Round 3
// 1124.838 us; speedup vs baseline: 2.4881x; 2.4881x over previous
//
#include <hip/hip_runtime.h>
#include <hip/hip_bf16.h>
#include <math.h>

constexpr int N = 65536;
constexpr int C = 192;
constexpr int O = 192;
constexpr int H = 384;
constexpr int E = 8;
constexpr int B = 4;
constexpr int R = 8;
constexpr int F = 64;
constexpr int GIN = C + F + 2;   // 258
constexpr int K = 10240;
constexpr int TM = 32;           // tokens per expert-tile

typedef unsigned short ushort;
typedef __attribute__((ext_vector_type(8))) short bf16x8;
typedef __attribute__((ext_vector_type(4))) float f32x4;
typedef __attribute__((ext_vector_type(4))) ushort ushort4v;

#define MFMA(a, b, c) __builtin_amdgcn_mfma_f32_16x16x32_bf16(a, b, c, 0, 0, 0)

__device__ inline ushort f2bf(float f) {
  union { float f; unsigned u; } v; v.f = f;
  unsigned r = v.u + 0x7FFFu + ((v.u >> 16) & 1u);
  return (ushort)(r >> 16);
}

__device__ inline unsigned long long dkey(double d) {
  unsigned long long u = (unsigned long long)__double_as_longlong(d);
  return (u & 0x8000000000000000ULL) ? ~u : (u | 0x8000000000000000ULL);
}

__device__ inline double wave_reduce_sum(double v) {
  #pragma unroll
  for (int off = 32; off; off >>= 1) v += __shfl_down(v, off);
  return v;  // valid on lane 0
}

// ---------- convert + transpose weights to bf16 ----------
__global__ __launch_bounds__(256) void convert_kernel(
    const float* __restrict__ W1, const float* __restrict__ W2,
    const float* __restrict__ A1, const float* __restrict__ B1,
    const float* __restrict__ A2, const float* __restrict__ B2,
    ushort* __restrict__ W1t, ushort* __restrict__ W2t,
    ushort* __restrict__ A1t, ushort* __restrict__ B1t,
    ushort* __restrict__ A2t, ushort* __restrict__ B2t) {
  const int s1 = E * H * C;      // W1t[e][h][c]
  const int s2 = E * O * H;      // W2t[e][o][h]
  const int s3 = E * 32 * C;     // A1t[e][br][c]
  const int s4 = E * H * 32;     // B1t[e][h][br]
  const int s5 = E * 32 * H;     // A2t[e][br][h]
  const int s6 = E * O * 32;     // B2t[e][o][br]
  int tid = blockIdx.x * 256 + threadIdx.x;
  if (tid < s1) {
    int e = tid / (H * C), rem = tid % (H * C), h = rem / C, c = rem % C;
    W1t[tid] = f2bf(W1[((size_t)e * C + c) * H + h]);
  } else if ((tid -= s1) < s2) {
    int e = tid / (O * H), rem = tid % (O * H), o = rem / H, h = rem % H;
    W2t[tid] = f2bf(W2[((size_t)e * H + h) * O + o]);
  } else if ((tid -= s2) < s3) {
    int e = tid / (32 * C), rem = tid % (32 * C), br = rem / C, c = rem % C;
    int b = br >> 3, r = br & 7;
    A1t[tid] = f2bf(A1[(((size_t)e * B + b) * C + c) * R + r]);
  } else if ((tid -= s3) < s4) {
    int e = tid / (H * 32), rem = tid % (H * 32), h = rem / 32, br = rem % 32;
    B1t[tid] = f2bf(B1[((size_t)e * 32 + br) * H + h]);
  } else if ((tid -= s4) < s5) {
    int e = tid / (32 * H), rem = tid % (32 * H), br = rem / H, h = rem % H;
    int b = br >> 3, r = br & 7;
    A2t[tid] = f2bf(A2[(((size_t)e * B + b) * H + h) * R + r]);
  } else if ((tid -= s5) < s6) {
    int e = tid / (O * 32), rem = tid % (O * 32), o = rem / 32, br = rem % 32;
    B2t[tid] = f2bf(B2[((size_t)e * 32 + br) * O + o]);
  }
}

// ---------- gate: Z = x@Wz (f64), residual stats, LN, logits ----------
__global__ __launch_bounds__(512) void gate_kernel(
    const float* __restrict__ x, const float* __restrict__ xp,
    const float* __restrict__ Wz, const float* __restrict__ ln_g,
    const float* __restrict__ ln_b, const float* __restrict__ Wg,
    const float* __restrict__ bg, double* __restrict__ logitsT) {
  __shared__ float Wzs[C * F];      // 48 KiB
  __shared__ float Wgs[GIN * E];    // ~8 KiB
  __shared__ float gs[GIN];
  __shared__ float bs[GIN];
  __shared__ float bgs[E];
  __shared__ float xsh[8][C];

  int tid = threadIdx.x;
  for (int i = tid; i < C * F; i += 512) Wzs[i] = Wz[i];
  for (int i = tid; i < GIN * E; i += 512) Wgs[i] = Wg[i];
  for (int i = tid; i < GIN; i += 512) { gs[i] = ln_g[i]; bs[i] = ln_b[i]; }
  if (tid < E) bgs[tid] = bg[tid];

  int wv = tid >> 6, lane = tid & 63;
  int n = blockIdx.x * 8 + wv;
  for (int i = lane; i < C; i += 64) xsh[wv][i] = x[(size_t)n * C + i];
  __syncthreads();

  // Z[lane] in f64
  double z = 0.0;
  for (int c = 0; c < C; ++c)
    z += (double)xsh[wv][c] * (double)Wzs[c * F + lane];

  // residual-hint stats
  double sa = 0.0, sa2 = 0.0;
  for (int i = lane; i < C; i += 64) {
    float d = xsh[wv][i] - xp[(size_t)n * C + i];
    float a = fabsf(d);
    sa += (double)a; sa2 += (double)a * (double)a;
  }
  #pragma unroll
  for (int off = 32; off; off >>= 1) {
    sa += __shfl_down(sa, off);
    sa2 += __shfl_down(sa2, off);
  }
  sa = __shfl(sa, 0); sa2 = __shfl(sa2, 0);
  double mean_a = sa * (1.0 / 192.0);
  double var_a = (sa2 - sa * sa * (1.0 / 192.0)) * (1.0 / 191.0);
  var_a = var_a > 0.0 ? var_a : 0.0;
  double mu = log1p(mean_a);
  double sdl = log1p(sqrt(var_a));

  // LayerNorm stats over et = [x(192), Z(64), mu, sd]
  double s = z, s2 = z * z;
  for (int i = lane; i < C; i += 64) {
    double v = (double)xsh[wv][i];
    s += v; s2 += v * v;
  }
  if (lane == 0) { s += mu; s2 += mu * mu; }
  if (lane == 1) { s += sdl; s2 += sdl * sdl; }
  #pragma unroll
  for (int off = 32; off; off >>= 1) {
    s += __shfl_down(s, off);
    s2 += __shfl_down(s2, off);
  }
  s = __shfl(s, 0); s2 = __shfl(s2, 0);
  double m_ = s * (1.0 / 258.0);
  double v_ = s2 * (1.0 / 258.0) - m_ * m_;
  v_ = v_ > 0.0 ? v_ : 0.0;
  double rstd = 1.0 / sqrt(v_ + 1e-5);

  double acc[E] = {0, 0, 0, 0, 0, 0, 0, 0};
  for (int i = lane; i < C; i += 64) {
    double nv = ((double)xsh[wv][i] - m_) * rstd * (double)gs[i] + (double)bs[i];
    #pragma unroll
    for (int e = 0; e < E; ++e) acc[e] += nv * (double)Wgs[i * E + e];
  }
  {
    int i = 192 + lane;
    double nv = (z - m_) * rstd * (double)gs[i] + (double)bs[i];
    #pragma unroll
    for (int e = 0; e < E; ++e) acc[e] += nv * (double)Wgs[i * E + e];
  }
  if (lane == 0) {
    double nv = (mu - m_) * rstd * (double)gs[256] + (double)bs[256];
    #pragma unroll
    for (int e = 0; e < E; ++e) acc[e] += nv * (double)Wgs[256 * E + e];
  }
  if (lane == 1) {
    double nv = (sdl - m_) * rstd * (double)gs[257] + (double)bs[257];
    #pragma unroll
    for (int e = 0; e < E; ++e) acc[e] += nv * (double)Wgs[257 * E + e];
  }
  #pragma unroll
  for (int e = 0; e < E; ++e) {
    double v = acc[e];
    #pragma unroll
    for (int off = 32; off; off >>= 1) v += __shfl_down(v, off);
    if (lane == 0) logitsT[(size_t)e * N + n] = v + (double)bgs[e];
  }
}

// ---------- per-expert exact top-K threshold via radix select ----------
__global__ __launch_bounds__(256) void select_kernel(
    const double* __restrict__ logitsT, unsigned long long* __restrict__ Tkey,
    int* __restrict__ tieCut) {
  int e = blockIdx.x;
  const double* L = logitsT + (size_t)e * N;
  __shared__ unsigned int hist[256];
  __shared__ unsigned long long spref;
  __shared__ int srem;
  __shared__ int sscan[256];
  int tid = threadIdx.x;
  if (tid == 0) { spref = 0ULL; srem = K; }
  __syncthreads();

  for (int pass = 7; pass >= 0; --pass) {
    hist[tid] = 0;
    __syncthreads();
    unsigned long long pref = spref;
    unsigned long long mhi = (pass == 7) ? 0ULL : (~0ULL << ((pass + 1) * 8));
    for (int i = tid; i < N; i += 256) {
      unsigned long long k = dkey(L[i]);
      if ((k & mhi) == pref)
        atomicAdd(&hist[(unsigned)((k >> (pass * 8)) & 0xFF)], 1u);
    }
    __syncthreads();
    if (tid == 0) {
      int rem = srem;
      int b = 255;
      for (; b > 0; --b) {
        int c = (int)hist[b];
        if (c >= rem) break;
        rem -= c;
      }
      srem = rem;
      spref = pref | ((unsigned long long)(unsigned)b << (pass * 8));
    }
    __syncthreads();
  }
  unsigned long long T = spref;
  int need = srem;

  int base = tid * (N / 256);
  int c = 0;
  for (int i = 0; i < N / 256; ++i) c += (dkey(L[base + i]) == T) ? 1 : 0;
  sscan[tid] = c;
  __syncthreads();
  for (int off = 1; off < 256; off <<= 1) {
    int v = sscan[tid];
    int add = (tid >= off) ? sscan[tid - off] : 0;
    __syncthreads();
    sscan[tid] = v + add;
    __syncthreads();
  }
  int incl = sscan[tid];
  int excl = incl - c;
  if (excl < need && need <= incl) {
    int target = need - 1 - excl;
    int seen = 0;
    for (int i = 0; i < N / 256; ++i) {
      if (dkey(L[base + i]) == T) {
        if (seen == target) { tieCut[e] = base + i; break; }
        ++seen;
      }
    }
  }
  if (tid == 0) Tkey[e] = T;
}

// ---------- routing: mask, fallback, top-2 softmax, aggregated dispatch ----------
__global__ __launch_bounds__(256) void route_kernel(
    const double* __restrict__ logitsT, const unsigned long long* __restrict__ Tkey,
    const int* __restrict__ tieCut, int* __restrict__ cnt,
    int* __restrict__ list_tok, float* __restrict__ list_w,
    double* __restrict__ importance) {
  int n = blockIdx.x * 256 + threadIdx.x;
  int lane = threadIdx.x & 63;
  double l[E];
  unsigned selbits = 0;
  #pragma unroll
  for (int e = 0; e < E; ++e) {
    l[e] = logitsT[(size_t)e * N + n];
    unsigned long long k = dkey(l[e]);
    unsigned long long T = Tkey[e];
    bool sel = (k > T) || (k == T && n <= tieCut[e]);
    if (sel) selbits |= (1u << e);
  }
  if (selbits == 0) {
    int best = 0; double bv = l[0];
    #pragma unroll
    for (int e = 1; e < E; ++e) if (l[e] > bv) { bv = l[e]; best = e; }
    selbits = (1u << best);
  }
  int i0 = -1, i1 = -1;
  double v0 = -1e300, v1 = -1e300;
  #pragma unroll
  for (int e = 0; e < E; ++e) {
    if (selbits & (1u << e)) {
      double v = l[e];
      if (v > v0) { v1 = v0; i1 = i0; v0 = v; i0 = e; }
      else if (v > v1) { v1 = v; i1 = e; }
    }
  }
  double w0 = 1.0, w1 = 0.0;
  if (i1 >= 0) {
    double e1 = exp(v1 - v0);
    w0 = 1.0 / (1.0 + e1);
    w1 = e1 / (1.0 + e1);
  }
  float w0f = (float)w0;
  float w1f = (float)w1;
  bool app1 = (i1 >= 0) && (w1f > 0.0f);

  unsigned long long below = (1ULL << lane) - 1ULL;
  #pragma unroll
  for (int e = 0; e < E; ++e) {
    unsigned long long m0 = __ballot(i0 == e);
    unsigned long long m1 = __ballot(app1 && i1 == e);
    int c = __popcll(m0) + __popcll(m1);
    int basep = 0;
    if (lane == 0 && c) basep = atomicAdd(&cnt[e], c);
    basep = __shfl(basep, 0);
    if (i0 == e) {
      int idx = basep + __popcll(m0 & below);
      list_tok[e * N + idx] = n;
      list_w[e * N + idx] = w0f;
    }
    if (app1 && i1 == e) {
      int idx = basep + __popcll(m0) + __popcll(m1 & below);
      list_tok[e * N + idx] = n;
      list_w[e * N + idx] = w1f;
    }
    double v = 0.0;
    if (i0 == e) v += (double)w0f;
    if (app1 && i1 == e) v += (double)w1f;
    v = wave_reduce_sum(v);
    if (lane == 0 && v != 0.0) unsafeAtomicAdd(&importance[e], v);
  }
}

// ---------- fused expert MLP via bf16 MFMA ----------
__global__ __launch_bounds__(256) void expert_kernel(
    const float* __restrict__ x, const float* __restrict__ bw,
    const float* __restrict__ b1g, const float* __restrict__ b2g,
    const ushort* __restrict__ W1t, const ushort* __restrict__ W2t,
    const ushort* __restrict__ A1t, const ushort* __restrict__ B1t,
    const ushort* __restrict__ A2t, const ushort* __restrict__ B2t,
    const int* __restrict__ cnt, const int* __restrict__ list_tok,
    const float* __restrict__ list_w, float* __restrict__ out) {
  int e = blockIdx.y;
  int ce = cnt[e];
  int start = blockIdx.x * TM;
  if (start >= ce) return;
  int m = ce - start; if (m > TM) m = TM;

  __shared__ ushort xs[TM][200];   // pitch 400B: 16B-aligned rows
  __shared__ ushort hs[TM][392];
  __shared__ ushort t1w[TM][40];
  __shared__ ushort t2w[TM][40];
  __shared__ int stok[TM];
  __shared__ float swt[TM];
  __shared__ float bws[TM][B];

  int tid = threadIdx.x;
  if (tid < TM) {
    int idx = start + (tid < m ? tid : 0);
    stok[tid] = list_tok[e * N + idx];
    swt[tid] = (tid < m) ? list_w[e * N + idx] : 0.0f;
  }
  __syncthreads();
  // x -> bf16 LDS: 48 float4 chunks per token (C=192)
  for (int u = tid; u < TM * 48; u += 256) {
    int t = u / 48, ch = u % 48;
    float4 v = *(const float4*)(x + (size_t)stok[t] * C + ch * 4);
    ushort4v o4;
    o4.x = f2bf(v.x); o4.y = f2bf(v.y); o4.z = f2bf(v.z); o4.w = f2bf(v.w);
    *(ushort4v*)&xs[t][ch * 4] = o4;
  }
  if (tid < TM * B) {
    int t = tid >> 2, b = tid & 3;
    bws[t][b] = bw[(size_t)stok[t] * B + b];
  }
  __syncthreads();

  int w = tid >> 6, lane = tid & 63, q = lane >> 4, mr = lane & 15;

  // ---- t1 = x @ A1e, scaled by 2*bw -> t1w (bf16, A-layout-ready)
  {
    int mt = w >> 1, nt = w & 1;
    const ushort* A1te = A1t + ((size_t)e * 32 + nt * 16 + mr) * C;
    f32x4 acc = {0.f, 0.f, 0.f, 0.f};
    #pragma unroll
    for (int ks = 0; ks < 6; ++ks) {
      bf16x8 a = *(const bf16x8*)&xs[mt * 16 + mr][ks * 32 + q * 8];
      bf16x8 b = *(const bf16x8*)(A1te + ks * 32 + q * 8);
      acc = MFMA(a, b, acc);
    }
    int brc = nt * 16 + mr, bb = brc >> 3;
    #pragma unroll
    for (int r = 0; r < 4; ++r) {
      int t = mt * 16 + q * 4 + r;
      t1w[t][brc] = f2bf(2.0f * acc[r] * bws[t][bb]);
    }
  }
  __syncthreads();

  // ---- h = gelu(x@W1 + b1 + t1w@B1)
  {
    const ushort* W1te = W1t + (size_t)e * H * C;
    const ushort* B1te = B1t + (size_t)e * H * 32;
    for (int ht = w * 6; ht < w * 6 + 6; ++ht) {
      int h = ht * 16 + mr;
      float bi = b1g[e * H + h];
      f32x4 acc0 = {bi, bi, bi, bi}, acc1 = acc0;
      bf16x8 bb = *(const bf16x8*)(B1te + h * 32 + q * 8);
      acc0 = MFMA(*(const bf16x8*)&t1w[mr][q * 8], bb, acc0);
      acc1 = MFMA(*(const bf16x8*)&t1w[16 + mr][q * 8], bb, acc1);
      #pragma unroll
      for (int ks = 0; ks < 6; ++ks) {
        bf16x8 wb = *(const bf16x8*)(W1te + (size_t)h * C + ks * 32 + q * 8);
        acc0 = MFMA(*(const bf16x8*)&xs[mr][ks * 32 + q * 8], wb, acc0);
        acc1 = MFMA(*(const bf16x8*)&xs[16 + mr][ks * 32 + q * 8], wb, acc1);
      }
      #pragma unroll
      for (int r = 0; r < 4; ++r) {
        float v0 = acc0[r], v1 = acc1[r];
        v0 = 0.5f * v0 * (1.0f + erff(v0 * 0.70710678118654752f));
        v1 = 0.5f * v1 * (1.0f + erff(v1 * 0.70710678118654752f));
        hs[q * 4 + r][h] = f2bf(v0);
        hs[16 + q * 4 + r][h] = f2bf(v1);
      }
    }
  }
  __syncthreads();

  // ---- t2 = h @ A2e, scaled by 2*bw -> t2w
  {
    int mt = w >> 1, nt = w & 1;
    const ushort* A2te = A2t + ((size_t)e * 32 + nt * 16 + mr) * H;
    f32x4 acc = {0.f, 0.f, 0.f, 0.f};
    #pragma unroll
    for (int ks = 0; ks < 12; ++ks) {
      bf16x8 a = *(const bf16x8*)&hs[mt * 16 + mr][ks * 32 + q * 8];
      bf16x8 b = *(const bf16x8*)(A2te + ks * 32 + q * 8);
      acc = MFMA(a, b, acc);
    }
    int brc = nt * 16 + mr, bb = brc >> 3;
    #pragma unroll
    for (int r = 0; r < 4; ++r) {
      int t = mt * 16 + q * 4 + r;
      t2w[t][brc] = f2bf(2.0f * acc[r] * bws[t][bb]);
    }
  }
  __syncthreads();

  // ---- y = h@W2 + b2 + t2w@B2, gate-weighted atomic scatter
  {
    const ushort* W2te = W2t + (size_t)e * O * H;
    const ushort* B2te = B2t + (size_t)e * O * 32;
    for (int ot = w * 3; ot < w * 3 + 3; ++ot) {
      int o = ot * 16 + mr;
      float bi = b2g[e * O + o];
      f32x4 acc0 = {bi, bi, bi, bi}, acc1 = acc0;
      bf16x8 bb = *(const bf16x8*)(B2te + o * 32 + q * 8);
      acc0 = MFMA(*(const bf16x8*)&t2w[mr][q * 8], bb, acc0);
      acc1 = MFMA(*(const bf16x8*)&t2w[16 + mr][q * 8], bb, acc1);
      #pragma unroll
      for (int ks = 0; ks < 12; ++ks) {
        bf16x8 wb = *(const bf16x8*)(W2te + (size_t)o * H + ks * 32 + q * 8);
        acc0 = MFMA(*(const bf16x8*)&hs[mr][ks * 32 + q * 8], wb, acc0);
        acc1 = MFMA(*(const bf16x8*)&hs[16 + mr][ks * 32 + q * 8], wb, acc1);
      }
      #pragma unroll
      for (int r = 0; r < 4; ++r) {
        int t0 = q * 4 + r, t1i = 16 + q * 4 + r;
        if (t0 < m)
          unsafeAtomicAdd(&out[(size_t)stok[t0] * O + o], swt[t0] * acc0[r]);
        if (t1i < m)
          unsafeAtomicAdd(&out[(size_t)stok[t1i] * O + o], swt[t1i] * acc1[r]);
      }
    }
  }
}

// ---------- load-balance aux loss ----------
__global__ void loss_kernel(const double* __restrict__ importance,
                            const int* __restrict__ cnt,
                            float* __restrict__ loss_out) {
  if (threadIdx.x == 0 && blockIdx.x == 0) {
    double im = 0.0, lm = 0.0;
    for (int e = 0; e < E; ++e) { im += importance[e]; lm += (double)cnt[e]; }
    im *= (1.0 / E); lm *= (1.0 / E);
    double iv = 0.0, lv = 0.0;
    for (int e = 0; e < E; ++e) {
      double di = importance[e] - im; iv += di * di;
      double dl = (double)cnt[e] - lm; lv += dl * dl;
    }
    iv *= (1.0 / E); lv *= (1.0 / E);
    double loss = (iv / (im * im + 1e-10) + lv / (lm * lm + 1e-10)) * 0.01;
    loss_out[0] = (float)loss;
  }
}

extern "C" void kernel_launch(void* const* d_in, const int* in_sizes, int n_in,
                              void* d_out, int out_size, void* d_ws, size_t ws_size,
                              hipStream_t stream) {
  const float* x    = (const float*)d_in[0];
  const float* bw   = (const float*)d_in[1];
  const float* xp   = (const float*)d_in[2];
  const float* Wz   = (const float*)d_in[3];
  const float* ln_g = (const float*)d_in[4];
  const float* ln_b = (const float*)d_in[5];
  const float* Wg   = (const float*)d_in[6];
  const float* bg   = (const float*)d_in[7];
  const float* W1   = (const float*)d_in[8];
  const float* b1   = (const float*)d_in[9];
  const float* W2   = (const float*)d_in[10];
  const float* b2   = (const float*)d_in[11];
  const float* A1   = (const float*)d_in[12];
  const float* B1   = (const float*)d_in[13];
  const float* A2   = (const float*)d_in[14];
  const float* B2   = (const float*)d_in[15];
  float* out = (float*)d_out;

  char* ws = (char*)d_ws;
  double* logitsT = (double*)ws;                                   // 4 MiB
  int*    list_tok = (int*)(ws + (size_t)4 * 1024 * 1024);         // 2 MiB
  float*  list_w   = (float*)(ws + (size_t)6 * 1024 * 1024);       // 2 MiB
  char*   hdr      = ws + (size_t)8 * 1024 * 1024;
  unsigned long long* Tkey = (unsigned long long*)hdr;             // 64 B
  int*    tieCut = (int*)(hdr + 64);                               // 32 B
  int*    cnt    = (int*)(hdr + 96);                               // 32 B
  double* importance = (double*)(hdr + 128);                       // 64 B
  ushort* W1t = (ushort*)(ws + (size_t)8 * 1024 * 1024 + 4096);
  ushort* W2t = W1t + (size_t)E * H * C;
  ushort* A1t = W2t + (size_t)E * O * H;
  ushort* B1t = A1t + (size_t)E * 32 * C;
  ushort* A2t = B1t + (size_t)E * H * 32;
  ushort* B2t = A2t + (size_t)E * 32 * H;

  hipMemsetAsync(d_out, 0, (size_t)(N * O + 1) * sizeof(float), stream);
  hipMemsetAsync(hdr + 96, 0, 96, stream);  // cnt + importance

  int convN = (E * H * C) * 2 + (E * 32 * C) * 2 + (E * H * 32) * 2;
  convert_kernel<<<(convN + 255) / 256, 256, 0, stream>>>(
      W1, W2, A1, B1, A2, B2, W1t, W2t, A1t, B1t, A2t, B2t);
  gate_kernel<<<N / 8, 512, 0, stream>>>(x, xp, Wz, ln_g, ln_b, Wg, bg, logitsT);
  select_kernel<<<E, 256, 0, stream>>>(logitsT, Tkey, tieCut);
  route_kernel<<<N / 256, 256, 0, stream>>>(logitsT, Tkey, tieCut, cnt,
                                            list_tok, list_w, importance);
  expert_kernel<<<dim3(N / TM, E), 256, 0, stream>>>(
      x, bw, b1, b2, W1t, W2t, A1t, B1t, A2t, B2t, cnt, list_tok, list_w, out);
  loss_kernel<<<1, 64, 0, stream>>>(importance, cnt, out + (size_t)N * O);
}

// Round 4
// 896.838 us; speedup vs baseline: 3.1206x; 1.2542x over previous
//
#include <hip/hip_runtime.h>
#include <hip/hip_bf16.h>
#include <math.h>

constexpr int N = 65536;
constexpr int C = 192;
constexpr int O = 192;
constexpr int H = 384;
constexpr int E = 8;
constexpr int B = 4;
constexpr int R = 8;
constexpr int F = 64;
constexpr int GIN = C + F + 2;   // 258
constexpr int K = 10240;
constexpr int TM = 32;           // tokens per expert-tile
constexpr int NBKT = 16384;      // 14-bit bucket histogram
constexpr int PCH = 16;          // chunks per expert for select passes
constexpr int CAP = 32768;       // candidate capacity per expert (>>10x margin)

typedef unsigned short ushort;
typedef __attribute__((ext_vector_type(8))) short bf16x8;
typedef __attribute__((ext_vector_type(4))) float f32x4;
typedef __attribute__((ext_vector_type(4))) ushort ushort4v;

#define MFMA(a, b, c) __builtin_amdgcn_mfma_f32_16x16x32_bf16(a, b, c, 0, 0, 0)

__device__ inline ushort f2bf(float f) {
  union { float f; unsigned u; } v; v.f = f;
  unsigned r = v.u + 0x7FFFu + ((v.u >> 16) & 1u);
  return (ushort)(r >> 16);
}

__device__ inline unsigned long long dkey(double d) {
  unsigned long long u = (unsigned long long)__double_as_longlong(d);
  return (u & 0x8000000000000000ULL) ? ~u : (u | 0x8000000000000000ULL);
}

__device__ inline double wave_reduce_sum(double v) {
  #pragma unroll
  for (int off = 32; off; off >>= 1) v += __shfl_down(v, off);
  return v;  // valid on lane 0
}

// ---------- convert + transpose weights to bf16 ----------
__global__ __launch_bounds__(256) void convert_kernel(
    const float* __restrict__ W1, const float* __restrict__ W2,
    const float* __restrict__ A1, const float* __restrict__ B1,
    const float* __restrict__ A2, const float* __restrict__ B2,
    ushort* __restrict__ W1t, ushort* __restrict__ W2t,
    ushort* __restrict__ A1t, ushort* __restrict__ B1t,
    ushort* __restrict__ A2t, ushort* __restrict__ B2t) {
  const int s1 = E * H * C;      // W1t[e][h][c]
  const int s2 = E * O * H;      // W2t[e][o][h]
  const int s3 = E * 32 * C;     // A1t[e][br][c]
  const int s4 = E * H * 32;     // B1t[e][h][br]
  const int s5 = E * 32 * H;     // A2t[e][br][h]
  const int s6 = E * O * 32;     // B2t[e][o][br]
  int tid = blockIdx.x * 256 + threadIdx.x;
  if (tid < s1) {
    int e = tid / (H * C), rem = tid % (H * C), h = rem / C, c = rem % C;
    W1t[tid] = f2bf(W1[((size_t)e * C + c) * H + h]);
  } else if ((tid -= s1) < s2) {
    int e = tid / (O * H), rem = tid % (O * H), o = rem / H, h = rem % H;
    W2t[tid] = f2bf(W2[((size_t)e * H + h) * O + o]);
  } else if ((tid -= s2) < s3) {
    int e = tid / (32 * C), rem = tid % (32 * C), br = rem / C, c = rem % C;
    int b = br >> 3, r = br & 7;
    A1t[tid] = f2bf(A1[(((size_t)e * B + b) * C + c) * R + r]);
  } else if ((tid -= s3) < s4) {
    int e = tid / (H * 32), rem = tid % (H * 32), h = rem / 32, br = rem % 32;
    B1t[tid] = f2bf(B1[((size_t)e * 32 + br) * H + h]);
  } else if ((tid -= s4) < s5) {
    int e = tid / (32 * H), rem = tid % (32 * H), br = rem / H, h = rem % H;
    int b = br >> 3, r = br & 7;
    A2t[tid] = f2bf(A2[(((size_t)e * B + b) * H + h) * R + r]);
  } else if ((tid -= s5) < s6) {
    int e = tid / (O * 32), rem = tid % (O * 32), o = rem / 32, br = rem % 32;
    B2t[tid] = f2bf(B2[((size_t)e * 32 + br) * O + o]);
  }
}

// ---------- gate: Z = x@Wz (f64), residual stats, LN, logits ----------
__global__ __launch_bounds__(512) void gate_kernel(
    const float* __restrict__ x, const float* __restrict__ xp,
    const float* __restrict__ Wz, const float* __restrict__ ln_g,
    const float* __restrict__ ln_b, const float* __restrict__ Wg,
    const float* __restrict__ bg, double* __restrict__ logitsT) {
  __shared__ float Wzs[C * F];      // 48 KiB
  __shared__ float Wgs[GIN * E];    // ~8 KiB
  __shared__ float gs[GIN];
  __shared__ float bs[GIN];
  __shared__ float bgs[E];
  __shared__ float xsh[8][C];

  int tid = threadIdx.x;
  for (int i = tid; i < C * F; i += 512) Wzs[i] = Wz[i];
  for (int i = tid; i < GIN * E; i += 512) Wgs[i] = Wg[i];
  for (int i = tid; i < GIN; i += 512) { gs[i] = ln_g[i]; bs[i] = ln_b[i]; }
  if (tid < E) bgs[tid] = bg[tid];

  int wv = tid >> 6, lane = tid & 63;
  int n = blockIdx.x * 8 + wv;
  for (int i = lane; i < C; i += 64) xsh[wv][i] = x[(size_t)n * C + i];
  __syncthreads();

  // Z[lane] in f64
  double z = 0.0;
  for (int c = 0; c < C; ++c)
    z += (double)xsh[wv][c] * (double)Wzs[c * F + lane];

  // residual-hint stats
  double sa = 0.0, sa2 = 0.0;
  for (int i = lane; i < C; i += 64) {
    float d = xsh[wv][i] - xp[(size_t)n * C + i];
    float a = fabsf(d);
    sa += (double)a; sa2 += (double)a * (double)a;
  }
  #pragma unroll
  for (int off = 32; off; off >>= 1) {
    sa += __shfl_down(sa, off);
    sa2 += __shfl_down(sa2, off);
  }
  sa = __shfl(sa, 0); sa2 = __shfl(sa2, 0);
  double mean_a = sa * (1.0 / 192.0);
  double var_a = (sa2 - sa * sa * (1.0 / 192.0)) * (1.0 / 191.0);
  var_a = var_a > 0.0 ? var_a : 0.0;
  double mu = log1p(mean_a);
  double sdl = log1p(sqrt(var_a));

  // LayerNorm stats over et = [x(192), Z(64), mu, sd]
  double s = z, s2 = z * z;
  for (int i = lane; i < C; i += 64) {
    double v = (double)xsh[wv][i];
    s += v; s2 += v * v;
  }
  if (lane == 0) { s += mu; s2 += mu * mu; }
  if (lane == 1) { s += sdl; s2 += sdl * sdl; }
  #pragma unroll
  for (int off = 32; off; off >>= 1) {
    s += __shfl_down(s, off);
    s2 += __shfl_down(s2, off);
  }
  s = __shfl(s, 0); s2 = __shfl(s2, 0);
  double m_ = s * (1.0 / 258.0);
  double v_ = s2 * (1.0 / 258.0) - m_ * m_;
  v_ = v_ > 0.0 ? v_ : 0.0;
  double rstd = 1.0 / sqrt(v_ + 1e-5);

  double acc[E] = {0, 0, 0, 0, 0, 0, 0, 0};
  for (int i = lane; i < C; i += 64) {
    double nv = ((double)xsh[wv][i] - m_) * rstd * (double)gs[i] + (double)bs[i];
    #pragma unroll
    for (int e = 0; e < E; ++e) acc[e] += nv * (double)Wgs[i * E + e];
  }
  {
    int i = 192 + lane;
    double nv = (z - m_) * rstd * (double)gs[i] + (double)bs[i];
    #pragma unroll
    for (int e = 0; e < E; ++e) acc[e] += nv * (double)Wgs[i * E + e];
  }
  if (lane == 0) {
    double nv = (mu - m_) * rstd * (double)gs[256] + (double)bs[256];
    #pragma unroll
    for (int e = 0; e < E; ++e) acc[e] += nv * (double)Wgs[256 * E + e];
  }
  if (lane == 1) {
    double nv = (sdl - m_) * rstd * (double)gs[257] + (double)bs[257];
    #pragma unroll
    for (int e = 0; e < E; ++e) acc[e] += nv * (double)Wgs[257 * E + e];
  }
  #pragma unroll
  for (int e = 0; e < E; ++e) {
    double v = acc[e];
    #pragma unroll
    for (int off = 32; off; off >>= 1) v += __shfl_down(v, off);
    if (lane == 0) logitsT[(size_t)e * N + n] = v + (double)bgs[e];
  }
}

// ---------- select stage A: per-chunk 14-bit bucket histogram ----------
__global__ __launch_bounds__(256) void selA_kernel(
    const double* __restrict__ logitsT, unsigned* __restrict__ gh) {
  __shared__ unsigned hist[NBKT];   // 64 KiB
  int e = blockIdx.y;
  const double* L = logitsT + (size_t)e * N + blockIdx.x * (N / PCH);
  for (int i = threadIdx.x; i < NBKT; i += 256) hist[i] = 0;
  __syncthreads();
  for (int i = threadIdx.x; i < N / PCH; i += 256) {
    unsigned long long k = dkey(L[i]);
    atomicAdd(&hist[(unsigned)(k >> 50)], 1u);
  }
  __syncthreads();
  unsigned* ghe = gh + (size_t)e * NBKT;
  for (int i = threadIdx.x; i < NBKT; i += 256) {
    unsigned v = hist[i];
    if (v) atomicAdd(&ghe[i], v);
  }
}

// ---------- select stage B: find boundary bucket + count above ----------
__global__ __launch_bounds__(256) void selB_kernel(
    const unsigned* __restrict__ gh, int* __restrict__ boundB,
    int* __restrict__ countAbove) {
  int e = blockIdx.x;
  const unsigned* ghe = gh + (size_t)e * NBKT;
  __shared__ unsigned chunkSum[256];
  unsigned s = 0;
  int base = threadIdx.x * 64;
  for (int i = 0; i < 64; ++i) s += ghe[base + i];
  chunkSum[threadIdx.x] = s;
  __syncthreads();
  if (threadIdx.x == 0) {
    long long acc = 0;
    for (int t = 255; t >= 0; --t) {
      if (acc + (long long)chunkSum[t] >= K) {
        for (int b = t * 64 + 63; b >= t * 64; --b) {
          unsigned hv = ghe[b];
          if (acc + (long long)hv >= K) {
            boundB[e] = b; countAbove[e] = (int)acc; return;
          }
          acc += hv;
        }
      }
      acc += chunkSum[t];
    }
    boundB[e] = 0; countAbove[e] = 0;  // unreachable safety
  }
}

// ---------- select stage C: compact boundary-bucket candidates ----------
__global__ __launch_bounds__(256) void selC_kernel(
    const double* __restrict__ logitsT, const int* __restrict__ boundB,
    int* __restrict__ candCnt, unsigned long long* __restrict__ candKey,
    int* __restrict__ candIdx) {
  int e = blockIdx.y;
  unsigned bb = (unsigned)boundB[e];
  int base = blockIdx.x * (N / PCH);
  const double* L = logitsT + (size_t)e * N;
  int lane = threadIdx.x & 63;
  unsigned long long below = (1ULL << lane) - 1ULL;
  for (int i0 = 0; i0 < N / PCH; i0 += 256) {
    int n = base + i0 + threadIdx.x;
    unsigned long long k = dkey(L[n]);
    bool match = ((unsigned)(k >> 50) == bb);
    unsigned long long mk = __ballot(match);
    if (match) {
      int leader = __ffsll((long long)mk) - 1;
      int cbase = 0;
      if (lane == leader) cbase = atomicAdd(&candCnt[e], __popcll(mk));
      cbase = __shfl(cbase, leader);
      int pos = cbase + __popcll(mk & below);
      if (pos < CAP) {
        candKey[(size_t)e * CAP + pos] = k;
        candIdx[(size_t)e * CAP + pos] = n;
      }
    }
  }
}

// ---------- select stage D: exact radix on candidates + tie cut ----------
__global__ __launch_bounds__(256) void selD_kernel(
    const unsigned long long* __restrict__ candKey, const int* __restrict__ candIdx,
    const int* __restrict__ candCnt, const int* __restrict__ countAbove,
    unsigned long long* __restrict__ Tkey, int* __restrict__ tieCut) {
  int e = blockIdx.x;
  int c = candCnt[e]; if (c > CAP) c = CAP;
  int need = K - countAbove[e];
  const unsigned long long* keys = candKey + (size_t)e * CAP;
  const int* idxs = candIdx + (size_t)e * CAP;
  __shared__ unsigned hist[256];
  __shared__ unsigned long long spref;
  __shared__ int srem;
  __shared__ int red[256];
  int tid = threadIdx.x;
  if (tid == 0) { spref = 0ULL; srem = need; }
  __syncthreads();
  for (int pass = 7; pass >= 0; --pass) {
    hist[tid] = 0;
    __syncthreads();
    unsigned long long pref = spref;
    unsigned long long mhi = (pass == 7) ? 0ULL : (~0ULL << ((pass + 1) * 8));
    for (int i = tid; i < c; i += 256) {
      unsigned long long k = keys[i];
      if ((k & mhi) == pref)
        atomicAdd(&hist[(unsigned)((k >> (pass * 8)) & 0xFF)], 1u);
    }
    __syncthreads();
    if (tid == 0) {
      int rem = srem;
      int b = 255;
      for (; b > 0; --b) {
        int cc = (int)hist[b];
        if (cc >= rem) break;
        rem -= cc;
      }
      srem = rem;
      spref = pref | ((unsigned long long)(unsigned)b << (pass * 8));
    }
    __syncthreads();
  }
  unsigned long long T = spref;
  int needT = srem;  // take needT lowest-index tokens among ==T
  // binary search: smallest idx0 with |{i: key==T, idx<=idx0}| >= needT
  int lo = 0, hi = N - 1;
  while (lo < hi) {
    int mid = (lo + hi) >> 1;
    int cnt = 0;
    for (int i = tid; i < c; i += 256)
      cnt += (keys[i] == T && idxs[i] <= mid) ? 1 : 0;
    red[tid] = cnt;
    __syncthreads();
    for (int off = 128; off; off >>= 1) {
      if (tid < off) red[tid] += red[tid + off];
      __syncthreads();
    }
    int total = red[0];
    __syncthreads();
    if (total >= needT) hi = mid; else lo = mid + 1;
  }
  if (tid == 0) { Tkey[e] = T; tieCut[e] = lo; }
}

// ---------- routing: mask, fallback, top-2 softmax, aggregated dispatch ----------
__global__ __launch_bounds__(256) void route_kernel(
    const double* __restrict__ logitsT, const unsigned long long* __restrict__ Tkey,
    const int* __restrict__ tieCut, int* __restrict__ cnt,
    int* __restrict__ list_tok, float* __restrict__ list_w,
    double* __restrict__ importance) {
  int n = blockIdx.x * 256 + threadIdx.x;
  int lane = threadIdx.x & 63;
  double l[E];
  unsigned selbits = 0;
  #pragma unroll
  for (int e = 0; e < E; ++e) {
    l[e] = logitsT[(size_t)e * N + n];
    unsigned long long k = dkey(l[e]);
    unsigned long long T = Tkey[e];
    bool sel = (k > T) || (k == T && n <= tieCut[e]);
    if (sel) selbits |= (1u << e);
  }
  if (selbits == 0) {
    int best = 0; double bv = l[0];
    #pragma unroll
    for (int e = 1; e < E; ++e) if (l[e] > bv) { bv = l[e]; best = e; }
    selbits = (1u << best);
  }
  int i0 = -1, i1 = -1;
  double v0 = -1e300, v1 = -1e300;
  #pragma unroll
  for (int e = 0; e < E; ++e) {
    if (selbits & (1u << e)) {
      double v = l[e];
      if (v > v0) { v1 = v0; i1 = i0; v0 = v; i0 = e; }
      else if (v > v1) { v1 = v; i1 = e; }
    }
  }
  double w0 = 1.0, w1 = 0.0;
  if (i1 >= 0) {
    double e1 = exp(v1 - v0);
    w0 = 1.0 / (1.0 + e1);
    w1 = e1 / (1.0 + e1);
  }
  float w0f = (float)w0;
  float w1f = (float)w1;
  bool app1 = (i1 >= 0) && (w1f > 0.0f);

  unsigned long long below = (1ULL << lane) - 1ULL;
  #pragma unroll
  for (int e = 0; e < E; ++e) {
    unsigned long long m0 = __ballot(i0 == e);
    unsigned long long m1 = __ballot(app1 && i1 == e);
    int c = __popcll(m0) + __popcll(m1);
    int basep = 0;
    if (lane == 0 && c) basep = atomicAdd(&cnt[e], c);
    basep = __shfl(basep, 0);
    if (i0 == e) {
      int idx = basep + __popcll(m0 & below);
      list_tok[e * N + idx] = n;
      list_w[e * N + idx] = w0f;
    }
    if (app1 && i1 == e) {
      int idx = basep + __popcll(m0) + __popcll(m1 & below);
      list_tok[e * N + idx] = n;
      list_w[e * N + idx] = w1f;
    }
    double v = 0.0;
    if (i0 == e) v += (double)w0f;
    if (app1 && i1 == e) v += (double)w1f;
    v = wave_reduce_sum(v);
    if (lane == 0 && v != 0.0) unsafeAtomicAdd(&importance[e], v);
  }
}

// ---------- fused expert MLP via bf16 MFMA ----------
__global__ __launch_bounds__(256) void expert_kernel(
    const float* __restrict__ x, const float* __restrict__ bw,
    const float* __restrict__ b1g, const float* __restrict__ b2g,
    const ushort* __restrict__ W1t, const ushort* __restrict__ W2t,
    const ushort* __restrict__ A1t, const ushort* __restrict__ B1t,
    const ushort* __restrict__ A2t, const ushort* __restrict__ B2t,
    const int* __restrict__ cnt, const int* __restrict__ list_tok,
    const float* __restrict__ list_w, float* __restrict__ out) {
  int e = blockIdx.y;
  int ce = cnt[e];
  int start = blockIdx.x * TM;
  if (start >= ce) return;
  int m = ce - start; if (m > TM) m = TM;

  __shared__ ushort xs[TM][200];   // pitch 400B: 16B-aligned rows
  __shared__ ushort hs[TM][392];
  __shared__ ushort t1w[TM][40];
  __shared__ ushort t2w[TM][40];
  __shared__ int stok[TM];
  __shared__ float swt[TM];
  __shared__ float bws[TM][B];

  int tid = threadIdx.x;
  if (tid < TM) {
    int idx = start + (tid < m ? tid : 0);
    stok[tid] = list_tok[e * N + idx];
    swt[tid] = (tid < m) ? list_w[e * N + idx] : 0.0f;
  }
  __syncthreads();
  // x -> bf16 LDS: 48 float4 chunks per token (C=192)
  for (int u = tid; u < TM * 48; u += 256) {
    int t = u / 48, ch = u % 48;
    float4 v = *(const float4*)(x + (size_t)stok[t] * C + ch * 4);
    ushort4v o4;
    o4.x = f2bf(v.x); o4.y = f2bf(v.y); o4.z = f2bf(v.z); o4.w = f2bf(v.w);
    *(ushort4v*)&xs[t][ch * 4] = o4;
  }
  if (tid < TM * B) {
    int t = tid >> 2, b = tid & 3;
    bws[t][b] = bw[(size_t)stok[t] * B + b];
  }
  __syncthreads();

  int w = tid >> 6, lane = tid & 63, q = lane >> 4, mr = lane & 15;

  // ---- t1 = x @ A1e, scaled by 2*bw -> t1w (bf16, A-layout-ready)
  {
    int mt = w >> 1, nt = w & 1;
    const ushort* A1te = A1t + ((size_t)e * 32 + nt * 16 + mr) * C;
    f32x4 acc = {0.f, 0.f, 0.f, 0.f};
    #pragma unroll
    for (int ks = 0; ks < 6; ++ks) {
      bf16x8 a = *(const bf16x8*)&xs[mt * 16 + mr][ks * 32 + q * 8];
      bf16x8 b = *(const bf16x8*)(A1te + ks * 32 + q * 8);
      acc = MFMA(a, b, acc);
    }
    int brc = nt * 16 + mr, bb = brc >> 3;
    #pragma unroll
    for (int r = 0; r < 4; ++r) {
      int t = mt * 16 + q * 4 + r;
      t1w[t][brc] = f2bf(2.0f * acc[r] * bws[t][bb]);
    }
  }
  __syncthreads();

  // ---- h = gelu(x@W1 + b1 + t1w@B1)
  {
    const ushort* W1te = W1t + (size_t)e * H * C;
    const ushort* B1te = B1t + (size_t)e * H * 32;
    for (int ht = w * 6; ht < w * 6 + 6; ++ht) {
      int h = ht * 16 + mr;
      float bi = b1g[e * H + h];
      f32x4 acc0 = {bi, bi, bi, bi}, acc1 = acc0;
      bf16x8 bb = *(const bf16x8*)(B1te + h * 32 + q * 8);
      acc0 = MFMA(*(const bf16x8*)&t1w[mr][q * 8], bb, acc0);
      acc1 = MFMA(*(const bf16x8*)&t1w[16 + mr][q * 8], bb, acc1);
      #pragma unroll
      for (int ks = 0; ks < 6; ++ks) {
        bf16x8 wb = *(const bf16x8*)(W1te + (size_t)h * C + ks * 32 + q * 8);
        acc0 = MFMA(*(const bf16x8*)&xs[mr][ks * 32 + q * 8], wb, acc0);
        acc1 = MFMA(*(const bf16x8*)&xs[16 + mr][ks * 32 + q * 8], wb, acc1);
      }
      #pragma unroll
      for (int r = 0; r < 4; ++r) {
        float v0 = acc0[r], v1 = acc1[r];
        v0 = 0.5f * v0 * (1.0f + erff(v0 * 0.70710678118654752f));
        v1 = 0.5f * v1 * (1.0f + erff(v1 * 0.70710678118654752f));
        hs[q * 4 + r][h] = f2bf(v0);
        hs[16 + q * 4 + r][h] = f2bf(v1);
      }
    }
  }
  __syncthreads();

  // ---- t2 = h @ A2e, scaled by 2*bw -> t2w
  {
    int mt = w >> 1, nt = w & 1;
    const ushort* A2te = A2t + ((size_t)e * 32 + nt * 16 + mr) * H;
    f32x4 acc = {0.f, 0.f, 0.f, 0.f};
    #pragma unroll
    for (int ks = 0; ks < 12; ++ks) {
      bf16x8 a = *(const bf16x8*)&hs[mt * 16 + mr][ks * 32 + q * 8];
      bf16x8 b = *(const bf16x8*)(A2te + ks * 32 + q * 8);
      acc = MFMA(a, b, acc);
    }
    int brc = nt * 16 + mr, bb = brc >> 3;
    #pragma unroll
    for (int r = 0; r < 4; ++r) {
      int t = mt * 16 + q * 4 + r;
      t2w[t][brc] = f2bf(2.0f * acc[r] * bws[t][bb]);
    }
  }
  __syncthreads();

  // ---- y = h@W2 + b2 + t2w@B2, gate-weighted atomic scatter
  {
    const ushort* W2te = W2t + (size_t)e * O * H;
    const ushort* B2te = B2t + (size_t)e * O * 32;
    for (int ot = w * 3; ot < w * 3 + 3; ++ot) {
      int o = ot * 16 + mr;
      float bi = b2g[e * O + o];
      f32x4 acc0 = {bi, bi, bi, bi}, acc1 = acc0;
      bf16x8 bb = *(const bf16x8*)(B2te + o * 32 + q * 8);
      acc0 = MFMA(*(const bf16x8*)&t2w[mr][q * 8], bb, acc0);
      acc1 = MFMA(*(const bf16x8*)&t2w[16 + mr][q * 8], bb, acc1);
      #pragma unroll
      for (int ks = 0; ks < 12; ++ks) {
        bf16x8 wb = *(const bf16x8*)(W2te + (size_t)o * H + ks * 32 + q * 8);
        acc0 = MFMA(*(const bf16x8*)&hs[mr][ks * 32 + q * 8], wb, acc0);
        acc1 = MFMA(*(const bf16x8*)&hs[16 + mr][ks * 32 + q * 8], wb, acc1);
      }
      #pragma unroll
      for (int r = 0; r < 4; ++r) {
        int t0 = q * 4 + r, t1i = 16 + q * 4 + r;
        if (t0 < m)
          unsafeAtomicAdd(&out[(size_t)stok[t0] * O + o], swt[t0] * acc0[r]);
        if (t1i < m)
          unsafeAtomicAdd(&out[(size_t)stok[t1i] * O + o], swt[t1i] * acc1[r]);
      }
    }
  }
}

// ---------- load-balance aux loss ----------
__global__ void loss_kernel(const double* __restrict__ importance,
                            const int* __restrict__ cnt,
                            float* __restrict__ loss_out) {
  if (threadIdx.x == 0 && blockIdx.x == 0) {
    double im = 0.0, lm = 0.0;
    for (int e = 0; e < E; ++e) { im += importance[e]; lm += (double)cnt[e]; }
    im *= (1.0 / E); lm *= (1.0 / E);
    double iv = 0.0, lv = 0.0;
    for (int e = 0; e < E; ++e) {
      double di = importance[e] - im; iv += di * di;
      double dl = (double)cnt[e] - lm; lv += dl * dl;
    }
    iv *= (1.0 / E); lv *= (1.0 / E);
    double loss = (iv / (im * im + 1e-10) + lv / (lm * lm + 1e-10)) * 0.01;
    loss_out[0] = (float)loss;
  }
}

extern "C" void kernel_launch(void* const* d_in, const int* in_sizes, int n_in,
                              void* d_out, int out_size, void* d_ws, size_t ws_size,
                              hipStream_t stream) {
  const float* x    = (const float*)d_in[0];
  const float* bw   = (const float*)d_in[1];
  const float* xp   = (const float*)d_in[2];
  const float* Wz   = (const float*)d_in[3];
  const float* ln_g = (const float*)d_in[4];
  const float* ln_b = (const float*)d_in[5];
  const float* Wg   = (const float*)d_in[6];
  const float* bg   = (const float*)d_in[7];
  const float* W1   = (const float*)d_in[8];
  const float* b1   = (const float*)d_in[9];
  const float* W2   = (const float*)d_in[10];
  const float* b2   = (const float*)d_in[11];
  const float* A1   = (const float*)d_in[12];
  const float* B1   = (const float*)d_in[13];
  const float* A2   = (const float*)d_in[14];
  const float* B2   = (const float*)d_in[15];
  float* out = (float*)d_out;

  const size_t MB = 1024 * 1024;
  char* ws = (char*)d_ws;
  double* logitsT = (double*)ws;                           // 4 MiB
  int*    list_tok = (int*)(ws + 4 * MB);                  // 2 MiB
  float*  list_w   = (float*)(ws + 6 * MB);                // 2 MiB
  char*   hdr      = ws + 8 * MB;                          // 4 KiB
  unsigned long long* Tkey = (unsigned long long*)hdr;     // @0
  int*    tieCut = (int*)(hdr + 64);                       // @64
  int*    cnt    = (int*)(hdr + 96);                       // @96
  double* importance = (double*)(hdr + 128);               // @128..192
  int*    boundB = (int*)(hdr + 256);
  int*    countAbove = (int*)(hdr + 288);
  int*    candCnt = (int*)(hdr + 320);
  ushort* W1t = (ushort*)(ws + 8 * MB + 4096);             // ~3 MiB of bf16 weights
  ushort* W2t = W1t + (size_t)E * H * C;
  ushort* A1t = W2t + (size_t)E * O * H;
  ushort* B1t = A1t + (size_t)E * 32 * C;
  ushort* A2t = B1t + (size_t)E * H * 32;
  ushort* B2t = A2t + (size_t)E * 32 * H;
  unsigned* gh = (unsigned*)(ws + 12 * MB);                // 512 KiB
  unsigned long long* candKey = (unsigned long long*)(ws + 13 * MB);  // 2 MiB
  int* candIdx = (int*)(ws + 15 * MB);                     // 1 MiB

  hipMemsetAsync(d_out, 0, (size_t)(N * O + 1) * sizeof(float), stream);
  hipMemsetAsync(hdr + 96, 0, 352 - 96, stream);  // cnt, importance, sel headers
  hipMemsetAsync(gh, 0, (size_t)E * NBKT * sizeof(unsigned), stream);

  int convN = (E * H * C) * 2 + (E * 32 * C) * 2 + (E * H * 32) * 2;
  convert_kernel<<<(convN + 255) / 256, 256, 0, stream>>>(
      W1, W2, A1, B1, A2, B2, W1t, W2t, A1t, B1t, A2t, B2t);
  gate_kernel<<<N / 8, 512, 0, stream>>>(x, xp, Wz, ln_g, ln_b, Wg, bg, logitsT);
  selA_kernel<<<dim3(PCH, E), 256, 0, stream>>>(logitsT, gh);
  selB_kernel<<<E, 256, 0, stream>>>(gh, boundB, countAbove);
  selC_kernel<<<dim3(PCH, E), 256, 0, stream>>>(logitsT, boundB, candCnt,
                                                candKey, candIdx);
  selD_kernel<<<E, 256, 0, stream>>>(candKey, candIdx, candCnt, countAbove,
                                     Tkey, tieCut);
  route_kernel<<<N / 256, 256, 0, stream>>>(logitsT, Tkey, tieCut, cnt,
                                            list_tok, list_w, importance);
  expert_kernel<<<dim3(N / TM, E), 256, 0, stream>>>(
      x, bw, b1, b2, W1t, W2t, A1t, B1t, A2t, B2t, cnt, list_tok, list_w, out);
  loss_kernel<<<1, 64, 0, stream>>>(importance, cnt, out + (size_t)N * O);
}